// Round 3
// baseline (12602.216 us; speedup 1.0000x reference)
//
#include <hip/hip_runtime.h>
#include <math.h>
#include <stdint.h>

constexpr int BATCH  = 512;
constexpr int NNODE  = 100;
constexpr int HDIM   = 256;
constexpr int NHEAD  = 8;
constexpr int DHEAD  = 32;
constexpr int NLAYER = 3;
constexpr int FDIM   = 512;
constexpr int MTOK   = BATCH * NNODE;   // 51200
constexpr int RLEN   = 200;             // route row length = 1 + 199

static __device__ __forceinline__ float wave_sum(float v) {
#pragma unroll
    for (int o = 32; o; o >>= 1) v += __shfl_xor(v, o);
    return v;
}
static __device__ __forceinline__ float wave_max(float v) {
#pragma unroll
    for (int o = 32; o; o >>= 1) v = fmaxf(v, __shfl_xor(v, o));
    return v;
}

// ---------------- node embedding: x = node_feats @ W_node + b_node ----------------
__global__ void k_embed(const float* __restrict__ nf, const float* __restrict__ W,
                        const float* __restrict__ bias, float* __restrict__ x) {
    int idx = blockIdx.x * 256 + threadIdx.x;   // over MTOK*HDIM
    int row = idx >> 8;
    int col = idx & 255;
    float a0 = nf[row * 3 + 0], a1 = nf[row * 3 + 1], a2 = nf[row * 3 + 2];
    x[idx] = fmaf(a0, W[col], fmaf(a1, W[256 + col], fmaf(a2, W[512 + col], bias[col])));
}

// ---------------- W-in-registers GEMM: C = op(A[M,K] @ W[K,N] + bias (+res)) -------
// Each wave owns 64 output columns (lane = col) and a 128-deep K-slice of W held in
// 128 VGPRs. A rows are staged into LDS cooperatively, then read as wave-uniform
// float4 broadcasts (no per-lane LDS traffic). KW waves split K; partials combined
// in LDS; epilogue distributed across waves.
template<int KW, int NG, int KSIZE, int NSIZE, bool RELU, bool RES>
__global__ __launch_bounds__(KW* NG * 64) void k_gemmw(const float* __restrict__ A, int lda,
                                                       const float* __restrict__ W,
                                                       const float* __restrict__ bias,
                                                       const float* __restrict__ res,
                                                       float* __restrict__ C) {
    constexpr int THREADS = KW * NG * 64;
    constexpr int KP      = KSIZE / KW;     // 128
    constexpr int NW      = NG * 64;        // cols per block
    constexpr int GROUP   = 16;             // rows staged per barrier
    constexpr int ROWS    = 128;            // rows per block
    static_assert(KP == 128, "K slice per wave must be 128");
    __shared__ alignas(16) float as[GROUP * KSIZE];
    __shared__ float red[KW * GROUP * NW];

    const int t    = threadIdx.x;
    const int wv   = t >> 6, lane = t & 63;
    const int kw   = wv % KW, ng = wv / KW;
    const int n0   = blockIdx.x * NW;
    const int n    = n0 + ng * 64 + lane;
    const int rbase = blockIdx.y * ROWS;

    // weight panel: W[kw*128 + r][n] for r in [0,128)
    float wreg[KP];
    {
        const float* wp = W + (size_t)(kw * KP) * NSIZE + n;
#pragma unroll
        for (int r = 0; r < KP; ++r) wreg[r] = wp[(size_t)r * NSIZE];
    }
    const float breg = bias[n];

    for (int g = 0; g < ROWS / GROUP; ++g) {
        const int row0 = rbase + g * GROUP;
        // stage GROUP rows of A into LDS (coalesced float4)
        constexpr int F4PT = (GROUP * KSIZE / 4) / THREADS;
#pragma unroll
        for (int it = 0; it < F4PT; ++it) {
            int id = it * THREADS + t;
            int r  = id / (KSIZE / 4), c = id % (KSIZE / 4);
            float4 v = *reinterpret_cast<const float4*>(&A[(size_t)(row0 + r) * lda + c * 4]);
            *reinterpret_cast<float4*>(&as[r * KSIZE + c * 4]) = v;
        }
        __syncthreads();
        // compute: per row, 32 uniform b128 reads + 128 FMA into 4 rotating accs
        for (int r = 0; r < GROUP; ++r) {
            const float4* ar = reinterpret_cast<const float4*>(&as[r * KSIZE + kw * KP]);
            float acc[4] = {0.f, 0.f, 0.f, 0.f};
#pragma unroll
            for (int c = 0; c < KP / 4; ++c) {
                float4 av = ar[c];
                acc[c & 3] = fmaf(av.x, wreg[4 * c + 0], acc[c & 3]);
                acc[c & 3] = fmaf(av.y, wreg[4 * c + 1], acc[c & 3]);
                acc[c & 3] = fmaf(av.z, wreg[4 * c + 2], acc[c & 3]);
                acc[c & 3] = fmaf(av.w, wreg[4 * c + 3], acc[c & 3]);
            }
            red[(kw * GROUP + r) * NW + ng * 64 + lane] = (acc[0] + acc[1]) + (acc[2] + acc[3]);
        }
        __syncthreads();
        // epilogue: each wave finishes GROUP/KW rows
        constexpr int RPW = GROUP / KW;
#pragma unroll
        for (int rr = 0; rr < RPW; ++rr) {
            int r = kw * RPW + rr;
            float s = 0.f;
#pragma unroll
            for (int k2 = 0; k2 < KW; ++k2) s += red[(k2 * GROUP + r) * NW + ng * 64 + lane];
            s += breg;
            if constexpr (RES) s += res[(size_t)(row0 + r) * NSIZE + n];
            if constexpr (RELU) s = fmaxf(s, 0.f);
            C[(size_t)(row0 + r) * NSIZE + n] = s;
        }
        // no barrier needed: next stage writes `as` (epilogue reads `red`), and the
        // stage barrier of g+1 orders red-reads before the next red-writes.
    }
}

// deterministic 32-dot, identical accumulation order in both passes
static __device__ __forceinline__ float dot32(const float* __restrict__ q,
                                              const float* __restrict__ k) {
    float a = 0.f, b = 0.f;
#pragma unroll
    for (int d = 0; d < 32; d += 2) {
        a = fmaf(q[d],     k[d],     a);
        b = fmaf(q[d + 1], k[d + 1], b);
    }
    return a + b;
}

// ---------------- attention: one wave per (b,h); K/V staged in LDS ----------------
// lane owns query rows (lane, lane+64); K/V rows read as wave-uniform LDS broadcasts
// (120cy latency vs ~300cy L2 — fixes the round-2 latency stall).
__global__ __launch_bounds__(64) void k_attn(const float* __restrict__ qkv,
                                             float* __restrict__ out) {
    __shared__ alignas(16) float ks[NNODE * 32];
    __shared__ alignas(16) float vs[NNODE * 32];
    const int b    = blockIdx.x >> 3;
    const int h    = blockIdx.x & 7;
    const int lane = threadIdx.x;
    const float* __restrict__ base = qkv + (size_t)b * NNODE * 768 + h * DHEAD;

    // stage K and V (800 float4 each) with per-lane coalesced-ish loads
    for (int idx = lane; idx < NNODE * 8; idx += 64) {
        int j = idx >> 3, c = idx & 7;
        float4 kv = *reinterpret_cast<const float4*>(base + (size_t)j * 768 + 256 + c * 4);
        float4 vv = *reinterpret_cast<const float4*>(base + (size_t)j * 768 + 512 + c * 4);
        *reinterpret_cast<float4*>(&ks[j * 32 + c * 4]) = kv;
        *reinterpret_cast<float4*>(&vs[j * 32 + c * 4]) = vv;
    }
    __syncthreads();

    const int  i1   = lane;
    const bool has2 = lane < (NNODE - 64);                  // 36 lanes have a 2nd row
    const int  i2   = has2 ? lane + 64 : 0;

    float q1[32], q2[32];
    {
        const float* p1 = base + (size_t)i1 * 768;
        const float* p2 = base + (size_t)i2 * 768;
#pragma unroll
        for (int c = 0; c < 8; ++c) {
            float4 a = *reinterpret_cast<const float4*>(p1 + c * 4);
            float4 e = *reinterpret_cast<const float4*>(p2 + c * 4);
            q1[4 * c + 0] = a.x; q1[4 * c + 1] = a.y; q1[4 * c + 2] = a.z; q1[4 * c + 3] = a.w;
            q2[4 * c + 0] = e.x; q2[4 * c + 1] = e.y; q2[4 * c + 2] = e.z; q2[4 * c + 3] = e.w;
        }
    }
    constexpr float scale = 0.17677669529663687f;           // 1/sqrt(32)

    // pass 1: exact row max
    float m1 = -INFINITY, m2 = -INFINITY;
    for (int j = 0; j < NNODE; ++j) {
        const float* kp = &ks[j * 32];
        float kk[32];
#pragma unroll
        for (int c = 0; c < 8; ++c) {
            float4 kv = *reinterpret_cast<const float4*>(kp + c * 4);
            kk[4 * c + 0] = kv.x; kk[4 * c + 1] = kv.y; kk[4 * c + 2] = kv.z; kk[4 * c + 3] = kv.w;
        }
        m1 = fmaxf(m1, dot32(q1, kk) * scale);
        m2 = fmaxf(m2, dot32(q2, kk) * scale);
    }

    // pass 2: exp-sum and P@V accumulation (in registers)
    float l1 = 0.f, l2 = 0.f;
    float o1[32] = {}, o2[32] = {};
    for (int j = 0; j < NNODE; ++j) {
        const float* kp = &ks[j * 32];
        const float* vp = &vs[j * 32];
        float kk[32];
#pragma unroll
        for (int c = 0; c < 8; ++c) {
            float4 kv = *reinterpret_cast<const float4*>(kp + c * 4);
            kk[4 * c + 0] = kv.x; kk[4 * c + 1] = kv.y; kk[4 * c + 2] = kv.z; kk[4 * c + 3] = kv.w;
        }
        float s1 = dot32(q1, kk) * scale;
        float s2 = dot32(q2, kk) * scale;
        float p1 = __expf(s1 - m1);
        float p2 = __expf(s2 - m2);
        l1 += p1;
        l2 += p2;
#pragma unroll
        for (int c = 0; c < 8; ++c) {
            float4 vv = *reinterpret_cast<const float4*>(vp + c * 4);
            o1[4 * c + 0] = fmaf(p1, vv.x, o1[4 * c + 0]);
            o1[4 * c + 1] = fmaf(p1, vv.y, o1[4 * c + 1]);
            o1[4 * c + 2] = fmaf(p1, vv.z, o1[4 * c + 2]);
            o1[4 * c + 3] = fmaf(p1, vv.w, o1[4 * c + 3]);
            o2[4 * c + 0] = fmaf(p2, vv.x, o2[4 * c + 0]);
            o2[4 * c + 1] = fmaf(p2, vv.y, o2[4 * c + 1]);
            o2[4 * c + 2] = fmaf(p2, vv.z, o2[4 * c + 2]);
            o2[4 * c + 3] = fmaf(p2, vv.w, o2[4 * c + 3]);
        }
    }

    const float inv1 = 1.f / l1;
    float* op1 = out + ((size_t)b * NNODE + i1) * 768 + h * DHEAD;
#pragma unroll
    for (int c = 0; c < 8; ++c) {
        float4 w = make_float4(o1[4 * c + 0] * inv1, o1[4 * c + 1] * inv1,
                               o1[4 * c + 2] * inv1, o1[4 * c + 3] * inv1);
        *reinterpret_cast<float4*>(op1 + c * 4) = w;
    }
    if (has2) {
        const float inv2 = 1.f / l2;
        float* op2 = out + ((size_t)b * NNODE + i2) * 768 + h * DHEAD;
#pragma unroll
        for (int c = 0; c < 8; ++c) {
            float4 w = make_float4(o2[4 * c + 0] * inv2, o2[4 * c + 1] * inv2,
                                   o2[4 * c + 2] * inv2, o2[4 * c + 3] * inv2);
            *reinterpret_cast<float4*>(op2 + c * 4) = w;
        }
    }
}

// ---------------- in-place LayerNorm over H=256, one wave per row ----------------
__global__ __launch_bounds__(256) void k_ln(float* __restrict__ x, const float* __restrict__ sc,
                                            const float* __restrict__ bp) {
    const int row = blockIdx.x * 4 + (threadIdx.x >> 6);
    const int lane = threadIdx.x & 63;
    float* rp = &x[(size_t)row * HDIM + lane * 4];
    float4 v = *reinterpret_cast<const float4*>(rp);
    float mean = wave_sum(v.x + v.y + v.z + v.w) * (1.f / 256.f);
    float d0 = v.x - mean, d1 = v.y - mean, d2 = v.z - mean, d3 = v.w - mean;
    float var = wave_sum(d0 * d0 + d1 * d1 + d2 * d2 + d3 * d3) * (1.f / 256.f);
    float inv = 1.f / sqrtf(var + 1e-5f);
    float4 sv = *reinterpret_cast<const float4*>(&sc[lane * 4]);
    float4 bv = *reinterpret_cast<const float4*>(&bp[lane * 4]);
    float4 ov;
    ov.x = fmaf(d0 * inv, sv.x, bv.x);
    ov.y = fmaf(d1 * inv, sv.y, bv.y);
    ov.z = fmaf(d2 * inv, sv.z, bv.z);
    ov.w = fmaf(d3 * inv, sv.w, bv.w);
    *reinterpret_cast<float4*>(rp) = ov;
}

// ---------------- Gram: S[b] = x[b] @ x[b]^T  (one block per batch) ----------------
__global__ __launch_bounds__(256) void k_gram(const float* __restrict__ x, float* __restrict__ S) {
    __shared__ alignas(16) float xs[16][128];
    const int b = blockIdx.x;
    const int t = threadIdx.x, tx = t & 15, ty = t >> 4;
    const int li = t >> 1, lko = (t & 1) * 8;
    float acc[8][8] = {};
    for (int kc = 0; kc < HDIM; kc += 16) {
        float va[8] = {0.f, 0.f, 0.f, 0.f, 0.f, 0.f, 0.f, 0.f};
        if (li < NNODE) {
            const float* p = &x[((size_t)b * NNODE + li) * HDIM + kc + lko];
            float4 u0 = *reinterpret_cast<const float4*>(p);
            float4 u1 = *reinterpret_cast<const float4*>(p + 4);
            va[0] = u0.x; va[1] = u0.y; va[2] = u0.z; va[3] = u0.w;
            va[4] = u1.x; va[5] = u1.y; va[6] = u1.z; va[7] = u1.w;
        }
        __syncthreads();
#pragma unroll
        for (int m = 0; m < 8; ++m) xs[lko + m][li] = va[m];
        __syncthreads();
#pragma unroll
        for (int k = 0; k < 16; ++k) {
            float ai[8], bj[8];
#pragma unroll
            for (int a = 0; a < 8; ++a) ai[a] = xs[k][ty + 16 * a];
#pragma unroll
            for (int c = 0; c < 8; ++c) bj[c] = xs[k][tx + 16 * c];
#pragma unroll
            for (int a = 0; a < 8; ++a)
#pragma unroll
                for (int c = 0; c < 8; ++c)
                    acc[a][c] = fmaf(ai[a], bj[c], acc[a][c]);
        }
    }
#pragma unroll
    for (int a = 0; a < 8; ++a) {
        int i = ty + 16 * a;
        if (i < NNODE) {
#pragma unroll
            for (int c = 0; c < 8; ++c) {
                int j = tx + 16 * c;
                if (j < NNODE) S[(size_t)b * NNODE * NNODE + (size_t)i * NNODE + j] = acc[a][c];
            }
        }
    }
}

// ---------------- routing decode: one wave (64 lanes) per batch, 199 sequential steps ----------------
__global__ __launch_bounds__(64) void k_route(const float* __restrict__ S, const float* __restrict__ demand,
                                              const float* __restrict__ capacity,
                                              const float* __restrict__ gumbel,
                                              float* __restrict__ out, int nsteps) {
    const int b = blockIdx.x;
    const int lane = threadIdx.x;
    const int j1 = lane, j2 = lane + 64;
    const bool v2 = (j2 < NNODE);
    const float d1 = demand[(size_t)b * NNODE + j1];
    const float d2 = v2 ? demand[(size_t)b * NNODE + j2] : 0.f;
    bool vis1 = (j1 == 0), vis2 = false;
    float cap = capacity[b];
    int cur = 0;
    float lp = 0.f;
    float* route = out + (size_t)b * RLEN;
    if (lane == 0) route[0] = 0.f;
    const float* Sb = S + (size_t)b * NNODE * NNODE;
    for (int s = 0; s < nsteps; ++s) {
        bool f1 = (!vis1) && (d1 <= cap);
        bool f2 = v2 && (!vis2) && (d2 <= cap);
        unsigned long long any = __ballot(f1 || f2);
        if (any == 0ULL) {
            if (lane == 0) route[1 + s] = 0.f;
            continue;
        }
        const float* sr = Sb + (size_t)cur * NNODE;
        const float* g = gumbel + ((size_t)s * BATCH + b) * NNODE;
        float sc1 = sr[j1];
        float sc2 = v2 ? sr[j2] : 0.f;
        float m1 = f1 ? sc1 : -1e9f;
        float m2 = f2 ? sc2 : -1e9f;
        // argmax(masked + g), first-index tie-break
        float k1 = m1 + g[j1];
        float k2 = v2 ? (m2 + g[j2]) : -INFINITY;
        float bk; int bi;
        if (k1 >= k2) { bk = k1; bi = j1; } else { bk = k2; bi = j2; }
#pragma unroll
        for (int off = 32; off; off >>= 1) {
            float ok = __shfl_xor(bk, off);
            int   oi = __shfl_xor(bi, off);
            if (ok > bk || (ok == bk && oi < bi)) { bk = ok; bi = oi; }
        }
        const int choice = bi;   // uniform across wave
        // log_softmax(masked)[choice]
        float mx = wave_max(fmaxf(m1, v2 ? m2 : -1e9f));
        float e = expf(m1 - mx) + (v2 ? expf(m2 - mx) : 0.f);
        e = wave_sum(e);
        float msel = __shfl((choice < 64) ? m1 : m2, choice & 63);
        float dsel = __shfl((choice < 64) ? d1 : d2, choice & 63);
        lp += msel - mx - logf(e);
        if (j1 == choice) vis1 = true;
        if (j2 == choice) vis2 = true;
        cap -= dsel;
        cur = choice;
        if (lane == 0) route[1 + s] = (float)choice;
    }
    if (lane == 0) out[(size_t)BATCH * RLEN + b] = lp;
}

extern "C" void kernel_launch(void* const* d_in, const int* in_sizes, int n_in,
                              void* d_out, int out_size, void* d_ws, size_t ws_size,
                              hipStream_t stream) {
    const float* node_feats = (const float*)d_in[0];
    const float* demand     = (const float*)d_in[1];
    const float* capacity   = (const float*)d_in[2];
    const float* gumbel     = (const float*)d_in[3];
    const float* W_node     = (const float*)d_in[4];
    const float* b_node     = (const float*)d_in[5];
    const float* qkv_w      = (const float*)d_in[6];
    const float* qkv_b      = (const float*)d_in[7];
    const float* out_w      = (const float*)d_in[8];
    const float* out_b      = (const float*)d_in[9];
    const float* ln1_s      = (const float*)d_in[10];
    const float* ln1_b      = (const float*)d_in[11];
    const float* w1         = (const float*)d_in[12];
    const float* b1         = (const float*)d_in[13];
    const float* w2         = (const float*)d_in[14];
    const float* b2         = (const float*)d_in[15];
    const float* ln2_s      = (const float*)d_in[16];
    const float* ln2_b      = (const float*)d_in[17];
    const int gsteps = in_sizes[3] / (BATCH * NNODE);   // 199

    float* x    = (float*)d_ws;                       // [MTOK][256]
    float* buf1 = x + (size_t)MTOK * HDIM;            // [MTOK][768] (qkv / ffn-hidden / S)
    float* S    = buf1;                               // reuse after encoder
    float* out  = (float*)d_out;

    k_embed<<<MTOK * HDIM / 256, 256, 0, stream>>>(node_feats, W_node, b_node, x);

    for (int l = 0; l < NLAYER; ++l) {
        // qkv = x @ qkv_w + qkv_b            [MTOK,768]
        k_gemmw<2, 2, 256, 768, false, false><<<dim3(6, MTOK / 128), 256, 0, stream>>>(
            x, 256, qkv_w + (size_t)l * 256 * 768, qkv_b + (size_t)l * 768, nullptr, buf1);
        // attention (o written into q-slice of buf1, row stride 768)
        k_attn<<<BATCH * NHEAD, 64, 0, stream>>>(buf1, buf1);
        // x = x + o @ out_w + out_b          (A = buf1 with lda=768)
        k_gemmw<2, 2, 256, 256, false, true><<<dim3(2, MTOK / 128), 256, 0, stream>>>(
            buf1, 768, out_w + (size_t)l * 256 * 256, out_b + (size_t)l * 256, x, x);
        k_ln<<<MTOK / 4, 256, 0, stream>>>(x, ln1_s + (size_t)l * 256, ln1_b + (size_t)l * 256);
        // h = relu(x @ w1 + b1)              [MTOK,512]
        k_gemmw<2, 2, 256, 512, true, false><<<dim3(4, MTOK / 128), 256, 0, stream>>>(
            x, 256, w1 + (size_t)l * 256 * 512, b1 + (size_t)l * 512, nullptr, buf1);
        // x = x + h @ w2 + b2                (K=512 -> 4-way K-split, 512 threads)
        k_gemmw<4, 2, 512, 256, false, true><<<dim3(2, MTOK / 128), 512, 0, stream>>>(
            buf1, 512, w2 + (size_t)l * 512 * 256, b2 + (size_t)l * 256, x, x);
        k_ln<<<MTOK / 4, 256, 0, stream>>>(x, ln2_s + (size_t)l * 256, ln2_b + (size_t)l * 256);
    }

    k_gram<<<BATCH, 256, 0, stream>>>(x, S);
    k_route<<<BATCH, 64, 0, stream>>>(S, demand, capacity, gumbel, out, gsteps);
    (void)n_in; (void)out_size; (void)ws_size;
}

// Round 4
// 3653.829 us; speedup vs baseline: 3.4490x; 3.4490x over previous
//
#include <hip/hip_runtime.h>
#include <math.h>
#include <stdint.h>

constexpr int BATCH  = 512;
constexpr int NNODE  = 100;
constexpr int HDIM   = 256;
constexpr int NHEAD  = 8;
constexpr int DHEAD  = 32;
constexpr int NLAYER = 3;
constexpr int FDIM   = 512;
constexpr int MTOK   = BATCH * NNODE;   // 51200
constexpr int RLEN   = 200;             // route row length = 1 + 199

static __device__ __forceinline__ float wave_sum(float v) {
#pragma unroll
    for (int o = 32; o; o >>= 1) v += __shfl_xor(v, o);
    return v;
}
static __device__ __forceinline__ float wave_max(float v) {
#pragma unroll
    for (int o = 32; o; o >>= 1) v = fmaxf(v, __shfl_xor(v, o));
    return v;
}

// ---------------- node embedding: x = node_feats @ W_node + b_node ----------------
__global__ void k_embed(const float* __restrict__ nf, const float* __restrict__ W,
                        const float* __restrict__ bias, float* __restrict__ x) {
    int idx = blockIdx.x * 256 + threadIdx.x;   // over MTOK*HDIM
    int row = idx >> 8;
    int col = idx & 255;
    float a0 = nf[row * 3 + 0], a1 = nf[row * 3 + 1], a2 = nf[row * 3 + 2];
    x[idx] = fmaf(a0, W[col], fmaf(a1, W[256 + col], fmaf(a2, W[512 + col], bias[col])));
}

// ---------------- tile GEMM, double-buffered: C = op(A[M,K] @ W[K,N] + bias (+res)) ----
// tile 128x128, BK=16, 256 threads, 8x8 per thread. One barrier per K-tile; the next
// tile's global loads are issued before the barrier so ~400cy of load latency hides
// under the 16 k-steps (~1000cy) of FMA on the current LDS buffer.
template<int KSIZE, int NSIZE, bool RELU, bool RES>
__global__ __launch_bounds__(256) void k_gemm(const float* __restrict__ A, int lda,
                                              const float* __restrict__ W,
                                              const float* __restrict__ bias,
                                              const float* __restrict__ res,
                                              float* __restrict__ C) {
    __shared__ alignas(16) float As[2][16][128];
    __shared__ alignas(16) float Bs[2][16][132];   // padded: conflict-free
    const int t  = threadIdx.x;
    const int tx = t & 15, ty = t >> 4;
    const int m0 = blockIdx.y * 128, n0 = blockIdx.x * 128;
    const int la_row = t >> 1, la_ko = (t & 1) * 8;
    const int lb_row = t >> 4, lb_col = (t & 15) * 8;
    float acc[2][4][2][4] = {};
    constexpr int NK = KSIZE / 16;

    const float* ap = &A[(size_t)(m0 + la_row) * lda + la_ko];
    const float* bp = &W[(size_t)lb_row * NSIZE + n0 + lb_col];

    // prologue: load tile 0 and write buffer 0
    float4 a0 = *reinterpret_cast<const float4*>(ap);
    float4 a1 = *reinterpret_cast<const float4*>(ap + 4);
    float4 b0 = *reinterpret_cast<const float4*>(bp);
    float4 b1 = *reinterpret_cast<const float4*>(bp + 4);
    As[0][la_ko + 0][la_row] = a0.x; As[0][la_ko + 1][la_row] = a0.y;
    As[0][la_ko + 2][la_row] = a0.z; As[0][la_ko + 3][la_row] = a0.w;
    As[0][la_ko + 4][la_row] = a1.x; As[0][la_ko + 5][la_row] = a1.y;
    As[0][la_ko + 6][la_row] = a1.z; As[0][la_ko + 7][la_row] = a1.w;
    *reinterpret_cast<float4*>(&Bs[0][lb_row][lb_col])     = b0;
    *reinterpret_cast<float4*>(&Bs[0][lb_row][lb_col + 4]) = b1;

    for (int kc = 0; kc < NK; ++kc) {
        const int cur = kc & 1;
        if (kc + 1 < NK) {   // issue next tile's loads (latency hidden by compute)
            const float* ap2 = ap + (kc + 1) * 16;
            a0 = *reinterpret_cast<const float4*>(ap2);
            a1 = *reinterpret_cast<const float4*>(ap2 + 4);
            const float* bp2 = bp + (size_t)(kc + 1) * 16 * NSIZE;
            b0 = *reinterpret_cast<const float4*>(bp2);
            b1 = *reinterpret_cast<const float4*>(bp2 + 4);
        }
        __syncthreads();     // buffer `cur` writes (prev iter) visible
#pragma unroll
        for (int k = 0; k < 16; ++k) {
            float ar[2][4], bc[2][4];
#pragma unroll
            for (int hh = 0; hh < 2; ++hh) {
                float4 av = *reinterpret_cast<const float4*>(&As[cur][k][hh * 64 + ty * 4]);
                ar[hh][0] = av.x; ar[hh][1] = av.y; ar[hh][2] = av.z; ar[hh][3] = av.w;
                float4 bv = *reinterpret_cast<const float4*>(&Bs[cur][k][hh * 64 + tx * 4]);
                bc[hh][0] = bv.x; bc[hh][1] = bv.y; bc[hh][2] = bv.z; bc[hh][3] = bv.w;
            }
#pragma unroll
            for (int rh = 0; rh < 2; ++rh)
#pragma unroll
            for (int r = 0; r < 4; ++r)
#pragma unroll
            for (int ch = 0; ch < 2; ++ch)
#pragma unroll
            for (int c = 0; c < 4; ++c)
                acc[rh][r][ch][c] = fmaf(ar[rh][r], bc[ch][c], acc[rh][r][ch][c]);
        }
        if (kc + 1 < NK) {   // write buffer cur^1 (safe: barrier at next iter top orders)
            const int nxt = cur ^ 1;
            As[nxt][la_ko + 0][la_row] = a0.x; As[nxt][la_ko + 1][la_row] = a0.y;
            As[nxt][la_ko + 2][la_row] = a0.z; As[nxt][la_ko + 3][la_row] = a0.w;
            As[nxt][la_ko + 4][la_row] = a1.x; As[nxt][la_ko + 5][la_row] = a1.y;
            As[nxt][la_ko + 6][la_row] = a1.z; As[nxt][la_ko + 7][la_row] = a1.w;
            *reinterpret_cast<float4*>(&Bs[nxt][lb_row][lb_col])     = b0;
            *reinterpret_cast<float4*>(&Bs[nxt][lb_row][lb_col + 4]) = b1;
        }
    }

#pragma unroll
    for (int ch = 0; ch < 2; ++ch) {
        float4 bv = *reinterpret_cast<const float4*>(&bias[n0 + ch * 64 + tx * 4]);
        float bb[4] = {bv.x, bv.y, bv.z, bv.w};
#pragma unroll
        for (int rh = 0; rh < 2; ++rh)
#pragma unroll
        for (int r = 0; r < 4; ++r) {
            size_t off = (size_t)(m0 + rh * 64 + ty * 4 + r) * NSIZE + n0 + ch * 64 + tx * 4;
            float o0 = acc[rh][r][ch][0] + bb[0];
            float o1 = acc[rh][r][ch][1] + bb[1];
            float o2 = acc[rh][r][ch][2] + bb[2];
            float o3 = acc[rh][r][ch][3] + bb[3];
            if constexpr (RES) {
                float4 rv = *reinterpret_cast<const float4*>(&res[off]);
                o0 += rv.x; o1 += rv.y; o2 += rv.z; o3 += rv.w;
            }
            if constexpr (RELU) {
                o0 = fmaxf(o0, 0.f); o1 = fmaxf(o1, 0.f);
                o2 = fmaxf(o2, 0.f); o3 = fmaxf(o3, 0.f);
            }
            float4 ov = make_float4(o0, o1, o2, o3);
            *reinterpret_cast<float4*>(&C[off]) = ov;
        }
    }
}

// deterministic 32-dot, identical accumulation order in both passes
static __device__ __forceinline__ float dot32(const float* __restrict__ q,
                                              const float* __restrict__ k) {
    float a = 0.f, b = 0.f;
#pragma unroll
    for (int d = 0; d < 32; d += 2) {
        a = fmaf(q[d],     k[d],     a);
        b = fmaf(q[d + 1], k[d + 1], b);
    }
    return a + b;
}

// ---------------- attention: one wave per (b,h); K/V staged in LDS ----------------
__global__ __launch_bounds__(64) void k_attn(const float* __restrict__ qkv,
                                             float* __restrict__ out) {
    __shared__ alignas(16) float ks[NNODE * 32];
    __shared__ alignas(16) float vs[NNODE * 32];
    const int b    = blockIdx.x >> 3;
    const int h    = blockIdx.x & 7;
    const int lane = threadIdx.x;
    const float* __restrict__ base = qkv + (size_t)b * NNODE * 768 + h * DHEAD;

    for (int idx = lane; idx < NNODE * 8; idx += 64) {
        int j = idx >> 3, c = idx & 7;
        float4 kv = *reinterpret_cast<const float4*>(base + (size_t)j * 768 + 256 + c * 4);
        float4 vv = *reinterpret_cast<const float4*>(base + (size_t)j * 768 + 512 + c * 4);
        *reinterpret_cast<float4*>(&ks[j * 32 + c * 4]) = kv;
        *reinterpret_cast<float4*>(&vs[j * 32 + c * 4]) = vv;
    }
    __syncthreads();

    const int  i1   = lane;
    const bool has2 = lane < (NNODE - 64);                  // 36 lanes have a 2nd row
    const int  i2   = has2 ? lane + 64 : 0;

    float q1[32], q2[32];
    {
        const float* p1 = base + (size_t)i1 * 768;
        const float* p2 = base + (size_t)i2 * 768;
#pragma unroll
        for (int c = 0; c < 8; ++c) {
            float4 a = *reinterpret_cast<const float4*>(p1 + c * 4);
            float4 e = *reinterpret_cast<const float4*>(p2 + c * 4);
            q1[4 * c + 0] = a.x; q1[4 * c + 1] = a.y; q1[4 * c + 2] = a.z; q1[4 * c + 3] = a.w;
            q2[4 * c + 0] = e.x; q2[4 * c + 1] = e.y; q2[4 * c + 2] = e.z; q2[4 * c + 3] = e.w;
        }
    }
    constexpr float scale = 0.17677669529663687f;           // 1/sqrt(32)

    // pass 1: exact row max
    float m1 = -INFINITY, m2 = -INFINITY;
    for (int j = 0; j < NNODE; ++j) {
        const float* kp = &ks[j * 32];
        float kk[32];
#pragma unroll
        for (int c = 0; c < 8; ++c) {
            float4 kv = *reinterpret_cast<const float4*>(kp + c * 4);
            kk[4 * c + 0] = kv.x; kk[4 * c + 1] = kv.y; kk[4 * c + 2] = kv.z; kk[4 * c + 3] = kv.w;
        }
        m1 = fmaxf(m1, dot32(q1, kk) * scale);
        m2 = fmaxf(m2, dot32(q2, kk) * scale);
    }

    // pass 2: exp-sum and P@V accumulation (in registers)
    float l1 = 0.f, l2 = 0.f;
    float o1[32] = {}, o2[32] = {};
    for (int j = 0; j < NNODE; ++j) {
        const float* kp = &ks[j * 32];
        const float* vp = &vs[j * 32];
        float kk[32];
#pragma unroll
        for (int c = 0; c < 8; ++c) {
            float4 kv = *reinterpret_cast<const float4*>(kp + c * 4);
            kk[4 * c + 0] = kv.x; kk[4 * c + 1] = kv.y; kk[4 * c + 2] = kv.z; kk[4 * c + 3] = kv.w;
        }
        float s1 = dot32(q1, kk) * scale;
        float s2 = dot32(q2, kk) * scale;
        float p1 = __expf(s1 - m1);
        float p2 = __expf(s2 - m2);
        l1 += p1;
        l2 += p2;
#pragma unroll
        for (int c = 0; c < 8; ++c) {
            float4 vv = *reinterpret_cast<const float4*>(vp + c * 4);
            o1[4 * c + 0] = fmaf(p1, vv.x, o1[4 * c + 0]);
            o1[4 * c + 1] = fmaf(p1, vv.y, o1[4 * c + 1]);
            o1[4 * c + 2] = fmaf(p1, vv.z, o1[4 * c + 2]);
            o1[4 * c + 3] = fmaf(p1, vv.w, o1[4 * c + 3]);
            o2[4 * c + 0] = fmaf(p2, vv.x, o2[4 * c + 0]);
            o2[4 * c + 1] = fmaf(p2, vv.y, o2[4 * c + 1]);
            o2[4 * c + 2] = fmaf(p2, vv.z, o2[4 * c + 2]);
            o2[4 * c + 3] = fmaf(p2, vv.w, o2[4 * c + 3]);
        }
    }

    const float inv1 = 1.f / l1;
    float* op1 = out + ((size_t)b * NNODE + i1) * 768 + h * DHEAD;
#pragma unroll
    for (int c = 0; c < 8; ++c) {
        float4 w = make_float4(o1[4 * c + 0] * inv1, o1[4 * c + 1] * inv1,
                               o1[4 * c + 2] * inv1, o1[4 * c + 3] * inv1);
        *reinterpret_cast<float4*>(op1 + c * 4) = w;
    }
    if (has2) {
        const float inv2 = 1.f / l2;
        float* op2 = out + ((size_t)b * NNODE + i2) * 768 + h * DHEAD;
#pragma unroll
        for (int c = 0; c < 8; ++c) {
            float4 w = make_float4(o2[4 * c + 0] * inv2, o2[4 * c + 1] * inv2,
                                   o2[4 * c + 2] * inv2, o2[4 * c + 3] * inv2);
            *reinterpret_cast<float4*>(op2 + c * 4) = w;
        }
    }
}

// ---------------- in-place LayerNorm over H=256, one wave per row ----------------
__global__ __launch_bounds__(256) void k_ln(float* __restrict__ x, const float* __restrict__ sc,
                                            const float* __restrict__ bp) {
    const int row = blockIdx.x * 4 + (threadIdx.x >> 6);
    const int lane = threadIdx.x & 63;
    float* rp = &x[(size_t)row * HDIM + lane * 4];
    float4 v = *reinterpret_cast<const float4*>(rp);
    float mean = wave_sum(v.x + v.y + v.z + v.w) * (1.f / 256.f);
    float d0 = v.x - mean, d1 = v.y - mean, d2 = v.z - mean, d3 = v.w - mean;
    float var = wave_sum(d0 * d0 + d1 * d1 + d2 * d2 + d3 * d3) * (1.f / 256.f);
    float inv = 1.f / sqrtf(var + 1e-5f);
    float4 sv = *reinterpret_cast<const float4*>(&sc[lane * 4]);
    float4 bv = *reinterpret_cast<const float4*>(&bp[lane * 4]);
    float4 ov;
    ov.x = fmaf(d0 * inv, sv.x, bv.x);
    ov.y = fmaf(d1 * inv, sv.y, bv.y);
    ov.z = fmaf(d2 * inv, sv.z, bv.z);
    ov.w = fmaf(d3 * inv, sv.w, bv.w);
    *reinterpret_cast<float4*>(rp) = ov;
}

// ---------------- Gram: S[b] = x[b] @ x[b]^T  (one block per batch) ----------------
__global__ __launch_bounds__(256) void k_gram(const float* __restrict__ x, float* __restrict__ S) {
    __shared__ alignas(16) float xs[16][128];
    const int b = blockIdx.x;
    const int t = threadIdx.x, tx = t & 15, ty = t >> 4;
    const int li = t >> 1, lko = (t & 1) * 8;
    float acc[8][8] = {};
    for (int kc = 0; kc < HDIM; kc += 16) {
        float va[8] = {0.f, 0.f, 0.f, 0.f, 0.f, 0.f, 0.f, 0.f};
        if (li < NNODE) {
            const float* p = &x[((size_t)b * NNODE + li) * HDIM + kc + lko];
            float4 u0 = *reinterpret_cast<const float4*>(p);
            float4 u1 = *reinterpret_cast<const float4*>(p + 4);
            va[0] = u0.x; va[1] = u0.y; va[2] = u0.z; va[3] = u0.w;
            va[4] = u1.x; va[5] = u1.y; va[6] = u1.z; va[7] = u1.w;
        }
        __syncthreads();
#pragma unroll
        for (int m = 0; m < 8; ++m) xs[lko + m][li] = va[m];
        __syncthreads();
#pragma unroll
        for (int k = 0; k < 16; ++k) {
            float ai[8], bj[8];
#pragma unroll
            for (int a = 0; a < 8; ++a) ai[a] = xs[k][ty + 16 * a];
#pragma unroll
            for (int c = 0; c < 8; ++c) bj[c] = xs[k][tx + 16 * c];
#pragma unroll
            for (int a = 0; a < 8; ++a)
#pragma unroll
                for (int c = 0; c < 8; ++c)
                    acc[a][c] = fmaf(ai[a], bj[c], acc[a][c]);
        }
    }
#pragma unroll
    for (int a = 0; a < 8; ++a) {
        int i = ty + 16 * a;
        if (i < NNODE) {
#pragma unroll
            for (int c = 0; c < 8; ++c) {
                int j = tx + 16 * c;
                if (j < NNODE) S[(size_t)b * NNODE * NNODE + (size_t)i * NNODE + j] = acc[a][c];
            }
        }
    }
}

// ---------------- routing decode: one wave per batch; S[b] staged in LDS ----------------
__global__ __launch_bounds__(64) void k_route(const float* __restrict__ S, const float* __restrict__ demand,
                                              const float* __restrict__ capacity,
                                              const float* __restrict__ gumbel,
                                              float* __restrict__ out, int nsteps) {
    __shared__ alignas(16) float Sl[NNODE * NNODE];   // 40 KB
    const int b = blockIdx.x;
    const int lane = threadIdx.x;
    const float* Sb = S + (size_t)b * NNODE * NNODE;
    for (int i = lane; i < NNODE * NNODE / 4; i += 64)
        *reinterpret_cast<float4*>(&Sl[i * 4]) = *reinterpret_cast<const float4*>(&Sb[i * 4]);
    __syncthreads();

    const int j1 = lane, j2 = lane + 64;
    const bool v2 = (j2 < NNODE);
    const float d1 = demand[(size_t)b * NNODE + j1];
    const float d2 = v2 ? demand[(size_t)b * NNODE + j2] : 0.f;
    bool vis1 = (j1 == 0), vis2 = false;
    float cap = capacity[b];
    int cur = 0;
    float lp = 0.f;
    float* route = out + (size_t)b * RLEN;
    if (lane == 0) route[0] = 0.f;
    for (int s = 0; s < nsteps; ++s) {
        bool f1 = (!vis1) && (d1 <= cap);
        bool f2 = v2 && (!vis2) && (d2 <= cap);
        unsigned long long any = __ballot(f1 || f2);
        if (any == 0ULL) {
            if (lane == 0) route[1 + s] = 0.f;
            continue;
        }
        const float* sr = &Sl[cur * NNODE];
        const float* g = gumbel + ((size_t)s * BATCH + b) * NNODE;
        float sc1 = sr[j1];
        float sc2 = v2 ? sr[j2] : 0.f;
        float m1 = f1 ? sc1 : -1e9f;
        float m2 = f2 ? sc2 : -1e9f;
        // argmax(masked + g), first-index tie-break
        float k1 = m1 + g[j1];
        float k2 = v2 ? (m2 + g[j2]) : -INFINITY;
        float bk; int bi;
        if (k1 >= k2) { bk = k1; bi = j1; } else { bk = k2; bi = j2; }
#pragma unroll
        for (int off = 32; off; off >>= 1) {
            float ok = __shfl_xor(bk, off);
            int   oi = __shfl_xor(bi, off);
            if (ok > bk || (ok == bk && oi < bi)) { bk = ok; bi = oi; }
        }
        const int choice = bi;   // uniform across wave
        // log_softmax(masked)[choice]
        float mx = wave_max(fmaxf(m1, v2 ? m2 : -1e9f));
        float e = expf(m1 - mx) + (v2 ? expf(m2 - mx) : 0.f);
        e = wave_sum(e);
        float msel = __shfl((choice < 64) ? m1 : m2, choice & 63);
        float dsel = __shfl((choice < 64) ? d1 : d2, choice & 63);
        lp += msel - mx - logf(e);
        if (j1 == choice) vis1 = true;
        if (j2 == choice) vis2 = true;
        cap -= dsel;
        cur = choice;
        if (lane == 0) route[1 + s] = (float)choice;
    }
    if (lane == 0) out[(size_t)BATCH * RLEN + b] = lp;
}

extern "C" void kernel_launch(void* const* d_in, const int* in_sizes, int n_in,
                              void* d_out, int out_size, void* d_ws, size_t ws_size,
                              hipStream_t stream) {
    const float* node_feats = (const float*)d_in[0];
    const float* demand     = (const float*)d_in[1];
    const float* capacity   = (const float*)d_in[2];
    const float* gumbel     = (const float*)d_in[3];
    const float* W_node     = (const float*)d_in[4];
    const float* b_node     = (const float*)d_in[5];
    const float* qkv_w      = (const float*)d_in[6];
    const float* qkv_b      = (const float*)d_in[7];
    const float* out_w      = (const float*)d_in[8];
    const float* out_b      = (const float*)d_in[9];
    const float* ln1_s      = (const float*)d_in[10];
    const float* ln1_b      = (const float*)d_in[11];
    const float* w1         = (const float*)d_in[12];
    const float* b1         = (const float*)d_in[13];
    const float* w2         = (const float*)d_in[14];
    const float* b2         = (const float*)d_in[15];
    const float* ln2_s      = (const float*)d_in[16];
    const float* ln2_b      = (const float*)d_in[17];
    const int gsteps = in_sizes[3] / (BATCH * NNODE);   // 199

    float* x    = (float*)d_ws;                       // [MTOK][256]
    float* buf1 = x + (size_t)MTOK * HDIM;            // [MTOK][768] (qkv / ffn-hidden / S)
    float* S    = buf1;                               // reuse after encoder
    float* out  = (float*)d_out;

    k_embed<<<MTOK * HDIM / 256, 256, 0, stream>>>(node_feats, W_node, b_node, x);

    for (int l = 0; l < NLAYER; ++l) {
        // qkv = x @ qkv_w + qkv_b            [MTOK,768]
        k_gemm<256, 768, false, false><<<dim3(6, MTOK / 128), 256, 0, stream>>>(
            x, 256, qkv_w + (size_t)l * 256 * 768, qkv_b + (size_t)l * 768, nullptr, buf1);
        // attention (o written into q-slice of buf1, row stride 768)
        k_attn<<<BATCH * NHEAD, 64, 0, stream>>>(buf1, buf1);
        // x = x + o @ out_w + out_b          (A = buf1 with lda=768)
        k_gemm<256, 256, false, true><<<dim3(2, MTOK / 128), 256, 0, stream>>>(
            buf1, 768, out_w + (size_t)l * 256 * 256, out_b + (size_t)l * 256, x, x);
        k_ln<<<MTOK / 4, 256, 0, stream>>>(x, ln1_s + (size_t)l * 256, ln1_b + (size_t)l * 256);
        // h = relu(x @ w1 + b1)              [MTOK,512]
        k_gemm<256, 512, true, false><<<dim3(4, MTOK / 128), 256, 0, stream>>>(
            x, 256, w1 + (size_t)l * 256 * 512, b1 + (size_t)l * 512, nullptr, buf1);
        // x = x + h @ w2 + b2
        k_gemm<512, 256, false, true><<<dim3(2, MTOK / 128), 256, 0, stream>>>(
            buf1, 512, w2 + (size_t)l * 512 * 256, b2 + (size_t)l * 256, x, x);
        k_ln<<<MTOK / 4, 256, 0, stream>>>(x, ln2_s + (size_t)l * 256, ln2_b + (size_t)l * 256);
    }

    k_gram<<<BATCH, 256, 0, stream>>>(x, S);
    k_route<<<BATCH, 64, 0, stream>>>(S, demand, capacity, gumbel, out, gsteps);
    (void)n_in; (void)out_size; (void)ws_size;
}

// Round 5
// 3115.159 us; speedup vs baseline: 4.0454x; 1.1729x over previous
//
#include <hip/hip_runtime.h>
#include <math.h>
#include <stdint.h>

constexpr int BATCH  = 512;
constexpr int NNODE  = 100;
constexpr int HDIM   = 256;
constexpr int NHEAD  = 8;
constexpr int DHEAD  = 32;
constexpr int NLAYER = 3;
constexpr int FDIM   = 512;
constexpr int MTOK   = BATCH * NNODE;   // 51200
constexpr int RLEN   = 200;             // route row length = 1 + 199

static __device__ __forceinline__ float wave_sum(float v) {
#pragma unroll
    for (int o = 32; o; o >>= 1) v += __shfl_xor(v, o);
    return v;
}
static __device__ __forceinline__ float wave_max(float v) {
#pragma unroll
    for (int o = 32; o; o >>= 1) v = fmaxf(v, __shfl_xor(v, o));
    return v;
}

// ---------------- node embedding: x = node_feats @ W_node + b_node ----------------
__global__ void k_embed(const float* __restrict__ nf, const float* __restrict__ W,
                        const float* __restrict__ bias, float* __restrict__ x) {
    int idx = blockIdx.x * 256 + threadIdx.x;   // over MTOK*HDIM
    int row = idx >> 8;
    int col = idx & 255;
    float a0 = nf[row * 3 + 0], a1 = nf[row * 3 + 1], a2 = nf[row * 3 + 2];
    x[idx] = fmaf(a0, W[col], fmaf(a1, W[256 + col], fmaf(a2, W[512 + col], bias[col])));
}

// ---------------- tile GEMM v1 (round-1 exact): 128x128 tile, 8x8/thread ----------------
template<int KSIZE, int NSIZE, bool RELU, bool RES>
__global__ __launch_bounds__(256) void k_gemm(const float* __restrict__ A, int lda,
                                              const float* __restrict__ W,
                                              const float* __restrict__ bias,
                                              const float* __restrict__ res,
                                              float* __restrict__ C) {
    __shared__ alignas(16) float As[16][128];
    __shared__ alignas(16) float Bs[16][132];   // padded: conflict-free writes
    const int t  = threadIdx.x;
    const int tx = t & 15, ty = t >> 4;
    const int m0 = blockIdx.y * 128, n0 = blockIdx.x * 128;
    const int la_row = t >> 1, la_ko = (t & 1) * 8;
    const int lb_row = t >> 4, lb_col = (t & 15) * 8;
    float acc[2][4][2][4] = {};

    for (int kc = 0; kc < KSIZE; kc += 16) {
        const float* ap = &A[(size_t)(m0 + la_row) * lda + kc + la_ko];
        float4 a0 = *reinterpret_cast<const float4*>(ap);
        float4 a1 = *reinterpret_cast<const float4*>(ap + 4);
        const float* bp = &W[(size_t)(kc + lb_row) * NSIZE + n0 + lb_col];
        float4 b0 = *reinterpret_cast<const float4*>(bp);
        float4 b1 = *reinterpret_cast<const float4*>(bp + 4);
        __syncthreads();
        As[la_ko + 0][la_row] = a0.x; As[la_ko + 1][la_row] = a0.y;
        As[la_ko + 2][la_row] = a0.z; As[la_ko + 3][la_row] = a0.w;
        As[la_ko + 4][la_row] = a1.x; As[la_ko + 5][la_row] = a1.y;
        As[la_ko + 6][la_row] = a1.z; As[la_ko + 7][la_row] = a1.w;
        *reinterpret_cast<float4*>(&Bs[lb_row][lb_col])     = b0;
        *reinterpret_cast<float4*>(&Bs[lb_row][lb_col + 4]) = b1;
        __syncthreads();
#pragma unroll
        for (int k = 0; k < 16; ++k) {
            float ar[2][4], bc[2][4];
#pragma unroll
            for (int hh = 0; hh < 2; ++hh) {
                float4 av = *reinterpret_cast<const float4*>(&As[k][hh * 64 + ty * 4]);
                ar[hh][0] = av.x; ar[hh][1] = av.y; ar[hh][2] = av.z; ar[hh][3] = av.w;
                float4 bv = *reinterpret_cast<const float4*>(&Bs[k][hh * 64 + tx * 4]);
                bc[hh][0] = bv.x; bc[hh][1] = bv.y; bc[hh][2] = bv.z; bc[hh][3] = bv.w;
            }
#pragma unroll
            for (int rh = 0; rh < 2; ++rh)
#pragma unroll
            for (int r = 0; r < 4; ++r)
#pragma unroll
            for (int ch = 0; ch < 2; ++ch)
#pragma unroll
            for (int c = 0; c < 4; ++c)
                acc[rh][r][ch][c] = fmaf(ar[rh][r], bc[ch][c], acc[rh][r][ch][c]);
        }
    }

#pragma unroll
    for (int ch = 0; ch < 2; ++ch) {
        float4 bv = *reinterpret_cast<const float4*>(&bias[n0 + ch * 64 + tx * 4]);
        float bb[4] = {bv.x, bv.y, bv.z, bv.w};
#pragma unroll
        for (int rh = 0; rh < 2; ++rh)
#pragma unroll
        for (int r = 0; r < 4; ++r) {
            size_t off = (size_t)(m0 + rh * 64 + ty * 4 + r) * NSIZE + n0 + ch * 64 + tx * 4;
            float o0 = acc[rh][r][ch][0] + bb[0];
            float o1 = acc[rh][r][ch][1] + bb[1];
            float o2 = acc[rh][r][ch][2] + bb[2];
            float o3 = acc[rh][r][ch][3] + bb[3];
            if constexpr (RES) {
                float4 rv = *reinterpret_cast<const float4*>(&res[off]);
                o0 += rv.x; o1 += rv.y; o2 += rv.z; o3 += rv.w;
            }
            if constexpr (RELU) {
                o0 = fmaxf(o0, 0.f); o1 = fmaxf(o1, 0.f);
                o2 = fmaxf(o2, 0.f); o3 = fmaxf(o3, 0.f);
            }
            float4 ov = make_float4(o0, o1, o2, o3);
            *reinterpret_cast<float4*>(&C[off]) = ov;
        }
    }
}

// ---------------- tile GEMM v2: 256x128 tile, 16x8/thread, reg-prefetch ----------------
// Halves LDS-read traffic per FMA (6 b128 / 128 FMA vs 4 / 64). 2 waves/SIMD at ~200
// VGPR; 128 independent FMAs per k-step give the ILP to fill the SIMD from one wave.
template<int KSIZE, int NSIZE, bool RELU, bool RES>
__global__ __launch_bounds__(256, 2) void k_gemm2(const float* __restrict__ A, int lda,
                                                  const float* __restrict__ W,
                                                  const float* __restrict__ bias,
                                                  const float* __restrict__ res,
                                                  float* __restrict__ C) {
    __shared__ alignas(16) float As[16][256];
    __shared__ alignas(16) float Bs[16][132];
    const int t  = threadIdx.x;
    const int tx = t & 15, ty = t >> 4;
    const int m0 = blockIdx.y * 256, n0 = blockIdx.x * 128;
    const int brow = t >> 4, bcol = (t & 15) * 8;
    float acc[4][4][2][4] = {};
    constexpr int NK = KSIZE / 16;

    const float* ap = &A[(size_t)(m0 + t) * lda];        // one row per thread
    const float* bp = &W[(size_t)brow * NSIZE + n0 + bcol];

    // prologue: tile-0 loads
    float4 a0 = *reinterpret_cast<const float4*>(ap);
    float4 a1 = *reinterpret_cast<const float4*>(ap + 4);
    float4 a2 = *reinterpret_cast<const float4*>(ap + 8);
    float4 a3 = *reinterpret_cast<const float4*>(ap + 12);
    float4 b0 = *reinterpret_cast<const float4*>(bp);
    float4 b1 = *reinterpret_cast<const float4*>(bp + 4);

    for (int kc = 0; kc < NK; ++kc) {
        __syncthreads();    // prev-iter LDS reads done
        As[0][t]  = a0.x; As[1][t]  = a0.y; As[2][t]  = a0.z; As[3][t]  = a0.w;
        As[4][t]  = a1.x; As[5][t]  = a1.y; As[6][t]  = a1.z; As[7][t]  = a1.w;
        As[8][t]  = a2.x; As[9][t]  = a2.y; As[10][t] = a2.z; As[11][t] = a2.w;
        As[12][t] = a3.x; As[13][t] = a3.y; As[14][t] = a3.z; As[15][t] = a3.w;
        *reinterpret_cast<float4*>(&Bs[brow][bcol])     = b0;
        *reinterpret_cast<float4*>(&Bs[brow][bcol + 4]) = b1;
        __syncthreads();
        if (kc + 1 < NK) {  // prefetch next tile; vmcnt wait lands at next LDS-write
            const float* ap2 = ap + (kc + 1) * 16;
            a0 = *reinterpret_cast<const float4*>(ap2);
            a1 = *reinterpret_cast<const float4*>(ap2 + 4);
            a2 = *reinterpret_cast<const float4*>(ap2 + 8);
            a3 = *reinterpret_cast<const float4*>(ap2 + 12);
            const float* bp2 = bp + (size_t)(kc + 1) * 16 * NSIZE;
            b0 = *reinterpret_cast<const float4*>(bp2);
            b1 = *reinterpret_cast<const float4*>(bp2 + 4);
        }
#pragma unroll
        for (int k = 0; k < 16; ++k) {
            float ar[4][4], bc[2][4];
#pragma unroll
            for (int g = 0; g < 4; ++g) {
                float4 av = *reinterpret_cast<const float4*>(&As[k][g * 64 + ty * 4]);
                ar[g][0] = av.x; ar[g][1] = av.y; ar[g][2] = av.z; ar[g][3] = av.w;
            }
#pragma unroll
            for (int h = 0; h < 2; ++h) {
                float4 bv = *reinterpret_cast<const float4*>(&Bs[k][h * 64 + tx * 4]);
                bc[h][0] = bv.x; bc[h][1] = bv.y; bc[h][2] = bv.z; bc[h][3] = bv.w;
            }
#pragma unroll
            for (int g = 0; g < 4; ++g)
#pragma unroll
            for (int r = 0; r < 4; ++r)
#pragma unroll
            for (int h = 0; h < 2; ++h)
#pragma unroll
            for (int c = 0; c < 4; ++c)
                acc[g][r][h][c] = fmaf(ar[g][r], bc[h][c], acc[g][r][h][c]);
        }
    }

#pragma unroll
    for (int h = 0; h < 2; ++h) {
        float4 bv = *reinterpret_cast<const float4*>(&bias[n0 + h * 64 + tx * 4]);
        float bb[4] = {bv.x, bv.y, bv.z, bv.w};
#pragma unroll
        for (int g = 0; g < 4; ++g)
#pragma unroll
        for (int r = 0; r < 4; ++r) {
            size_t off = (size_t)(m0 + g * 64 + ty * 4 + r) * NSIZE + n0 + h * 64 + tx * 4;
            float o0 = acc[g][r][h][0] + bb[0];
            float o1 = acc[g][r][h][1] + bb[1];
            float o2 = acc[g][r][h][2] + bb[2];
            float o3 = acc[g][r][h][3] + bb[3];
            if constexpr (RES) {
                float4 rv = *reinterpret_cast<const float4*>(&res[off]);
                o0 += rv.x; o1 += rv.y; o2 += rv.z; o3 += rv.w;
            }
            if constexpr (RELU) {
                o0 = fmaxf(o0, 0.f); o1 = fmaxf(o1, 0.f);
                o2 = fmaxf(o2, 0.f); o3 = fmaxf(o3, 0.f);
            }
            float4 ov = make_float4(o0, o1, o2, o3);
            *reinterpret_cast<float4*>(&C[off]) = ov;
        }
    }
}

// deterministic 32-dot, identical accumulation order in both passes
static __device__ __forceinline__ float dot32(const float* __restrict__ q,
                                              const float* __restrict__ k) {
    float a = 0.f, b = 0.f;
#pragma unroll
    for (int d = 0; d < 32; d += 2) {
        a = fmaf(q[d],     k[d],     a);
        b = fmaf(q[d + 1], k[d + 1], b);
    }
    return a + b;
}

// ---------------- attention: one wave per (b,h); K/V staged in LDS ----------------
__global__ __launch_bounds__(64) void k_attn(const float* __restrict__ qkv,
                                             float* __restrict__ out) {
    __shared__ alignas(16) float ks[NNODE * 32];
    __shared__ alignas(16) float vs[NNODE * 32];
    const int b    = blockIdx.x >> 3;
    const int h    = blockIdx.x & 7;
    const int lane = threadIdx.x;
    const float* __restrict__ base = qkv + (size_t)b * NNODE * 768 + h * DHEAD;

    for (int idx = lane; idx < NNODE * 8; idx += 64) {
        int j = idx >> 3, c = idx & 7;
        float4 kv = *reinterpret_cast<const float4*>(base + (size_t)j * 768 + 256 + c * 4);
        float4 vv = *reinterpret_cast<const float4*>(base + (size_t)j * 768 + 512 + c * 4);
        *reinterpret_cast<float4*>(&ks[j * 32 + c * 4]) = kv;
        *reinterpret_cast<float4*>(&vs[j * 32 + c * 4]) = vv;
    }
    __syncthreads();

    const int  i1   = lane;
    const bool has2 = lane < (NNODE - 64);                  // 36 lanes have a 2nd row
    const int  i2   = has2 ? lane + 64 : 0;

    float q1[32], q2[32];
    {
        const float* p1 = base + (size_t)i1 * 768;
        const float* p2 = base + (size_t)i2 * 768;
#pragma unroll
        for (int c = 0; c < 8; ++c) {
            float4 a = *reinterpret_cast<const float4*>(p1 + c * 4);
            float4 e = *reinterpret_cast<const float4*>(p2 + c * 4);
            q1[4 * c + 0] = a.x; q1[4 * c + 1] = a.y; q1[4 * c + 2] = a.z; q1[4 * c + 3] = a.w;
            q2[4 * c + 0] = e.x; q2[4 * c + 1] = e.y; q2[4 * c + 2] = e.z; q2[4 * c + 3] = e.w;
        }
    }
    constexpr float scale = 0.17677669529663687f;           // 1/sqrt(32)

    // pass 1: exact row max
    float m1 = -INFINITY, m2 = -INFINITY;
    for (int j = 0; j < NNODE; ++j) {
        const float* kp = &ks[j * 32];
        float kk[32];
#pragma unroll
        for (int c = 0; c < 8; ++c) {
            float4 kv = *reinterpret_cast<const float4*>(kp + c * 4);
            kk[4 * c + 0] = kv.x; kk[4 * c + 1] = kv.y; kk[4 * c + 2] = kv.z; kk[4 * c + 3] = kv.w;
        }
        m1 = fmaxf(m1, dot32(q1, kk) * scale);
        m2 = fmaxf(m2, dot32(q2, kk) * scale);
    }

    // pass 2: exp-sum and P@V accumulation (in registers)
    float l1 = 0.f, l2 = 0.f;
    float o1[32] = {}, o2[32] = {};
    for (int j = 0; j < NNODE; ++j) {
        const float* kp = &ks[j * 32];
        const float* vp = &vs[j * 32];
        float kk[32];
#pragma unroll
        for (int c = 0; c < 8; ++c) {
            float4 kv = *reinterpret_cast<const float4*>(kp + c * 4);
            kk[4 * c + 0] = kv.x; kk[4 * c + 1] = kv.y; kk[4 * c + 2] = kv.z; kk[4 * c + 3] = kv.w;
        }
        float s1 = dot32(q1, kk) * scale;
        float s2 = dot32(q2, kk) * scale;
        float p1 = __expf(s1 - m1);
        float p2 = __expf(s2 - m2);
        l1 += p1;
        l2 += p2;
#pragma unroll
        for (int c = 0; c < 8; ++c) {
            float4 vv = *reinterpret_cast<const float4*>(vp + c * 4);
            o1[4 * c + 0] = fmaf(p1, vv.x, o1[4 * c + 0]);
            o1[4 * c + 1] = fmaf(p1, vv.y, o1[4 * c + 1]);
            o1[4 * c + 2] = fmaf(p1, vv.z, o1[4 * c + 2]);
            o1[4 * c + 3] = fmaf(p1, vv.w, o1[4 * c + 3]);
            o2[4 * c + 0] = fmaf(p2, vv.x, o2[4 * c + 0]);
            o2[4 * c + 1] = fmaf(p2, vv.y, o2[4 * c + 1]);
            o2[4 * c + 2] = fmaf(p2, vv.z, o2[4 * c + 2]);
            o2[4 * c + 3] = fmaf(p2, vv.w, o2[4 * c + 3]);
        }
    }

    const float inv1 = 1.f / l1;
    float* op1 = out + ((size_t)b * NNODE + i1) * 768 + h * DHEAD;
#pragma unroll
    for (int c = 0; c < 8; ++c) {
        float4 w = make_float4(o1[4 * c + 0] * inv1, o1[4 * c + 1] * inv1,
                               o1[4 * c + 2] * inv1, o1[4 * c + 3] * inv1);
        *reinterpret_cast<float4*>(op1 + c * 4) = w;
    }
    if (has2) {
        const float inv2 = 1.f / l2;
        float* op2 = out + ((size_t)b * NNODE + i2) * 768 + h * DHEAD;
#pragma unroll
        for (int c = 0; c < 8; ++c) {
            float4 w = make_float4(o2[4 * c + 0] * inv2, o2[4 * c + 1] * inv2,
                                   o2[4 * c + 2] * inv2, o2[4 * c + 3] * inv2);
            *reinterpret_cast<float4*>(op2 + c * 4) = w;
        }
    }
}

// ---------------- in-place LayerNorm over H=256, one wave per row ----------------
__global__ __launch_bounds__(256) void k_ln(float* __restrict__ x, const float* __restrict__ sc,
                                            const float* __restrict__ bp) {
    const int row = blockIdx.x * 4 + (threadIdx.x >> 6);
    const int lane = threadIdx.x & 63;
    float* rp = &x[(size_t)row * HDIM + lane * 4];
    float4 v = *reinterpret_cast<const float4*>(rp);
    float mean = wave_sum(v.x + v.y + v.z + v.w) * (1.f / 256.f);
    float d0 = v.x - mean, d1 = v.y - mean, d2 = v.z - mean, d3 = v.w - mean;
    float var = wave_sum(d0 * d0 + d1 * d1 + d2 * d2 + d3 * d3) * (1.f / 256.f);
    float inv = 1.f / sqrtf(var + 1e-5f);
    float4 sv = *reinterpret_cast<const float4*>(&sc[lane * 4]);
    float4 bv = *reinterpret_cast<const float4*>(&bp[lane * 4]);
    float4 ov;
    ov.x = fmaf(d0 * inv, sv.x, bv.x);
    ov.y = fmaf(d1 * inv, sv.y, bv.y);
    ov.z = fmaf(d2 * inv, sv.z, bv.z);
    ov.w = fmaf(d3 * inv, sv.w, bv.w);
    *reinterpret_cast<float4*>(rp) = ov;
}

// ---------------- Gram: S[b] = x[b] @ x[b]^T  (one block per batch) ----------------
__global__ __launch_bounds__(256) void k_gram(const float* __restrict__ x, float* __restrict__ S) {
    __shared__ alignas(16) float xs[16][128];
    const int b = blockIdx.x;
    const int t = threadIdx.x, tx = t & 15, ty = t >> 4;
    const int li = t >> 1, lko = (t & 1) * 8;
    float acc[8][8] = {};
    for (int kc = 0; kc < HDIM; kc += 16) {
        float va[8] = {0.f, 0.f, 0.f, 0.f, 0.f, 0.f, 0.f, 0.f};
        if (li < NNODE) {
            const float* p = &x[((size_t)b * NNODE + li) * HDIM + kc + lko];
            float4 u0 = *reinterpret_cast<const float4*>(p);
            float4 u1 = *reinterpret_cast<const float4*>(p + 4);
            va[0] = u0.x; va[1] = u0.y; va[2] = u0.z; va[3] = u0.w;
            va[4] = u1.x; va[5] = u1.y; va[6] = u1.z; va[7] = u1.w;
        }
        __syncthreads();
#pragma unroll
        for (int m = 0; m < 8; ++m) xs[lko + m][li] = va[m];
        __syncthreads();
#pragma unroll
        for (int k = 0; k < 16; ++k) {
            float ai[8], bj[8];
#pragma unroll
            for (int a = 0; a < 8; ++a) ai[a] = xs[k][ty + 16 * a];
#pragma unroll
            for (int c = 0; c < 8; ++c) bj[c] = xs[k][tx + 16 * c];
#pragma unroll
            for (int a = 0; a < 8; ++a)
#pragma unroll
                for (int c = 0; c < 8; ++c)
                    acc[a][c] = fmaf(ai[a], bj[c], acc[a][c]);
        }
    }
#pragma unroll
    for (int a = 0; a < 8; ++a) {
        int i = ty + 16 * a;
        if (i < NNODE) {
#pragma unroll
            for (int c = 0; c < 8; ++c) {
                int j = tx + 16 * c;
                if (j < NNODE) S[(size_t)b * NNODE * NNODE + (size_t)i * NNODE + j] = acc[a][c];
            }
        }
    }
}

// ---------------- routing decode: one wave per batch; S[b] staged in LDS ----------------
__global__ __launch_bounds__(64) void k_route(const float* __restrict__ S, const float* __restrict__ demand,
                                              const float* __restrict__ capacity,
                                              const float* __restrict__ gumbel,
                                              float* __restrict__ out, int nsteps) {
    __shared__ alignas(16) float Sl[NNODE * NNODE];   // 40 KB
    const int b = blockIdx.x;
    const int lane = threadIdx.x;
    const float* Sb = S + (size_t)b * NNODE * NNODE;
    for (int i = lane; i < NNODE * NNODE / 4; i += 64)
        *reinterpret_cast<float4*>(&Sl[i * 4]) = *reinterpret_cast<const float4*>(&Sb[i * 4]);
    __syncthreads();

    const int j1 = lane, j2 = lane + 64;
    const bool v2 = (j2 < NNODE);
    const float d1 = demand[(size_t)b * NNODE + j1];
    const float d2 = v2 ? demand[(size_t)b * NNODE + j2] : 0.f;
    bool vis1 = (j1 == 0), vis2 = false;
    float cap = capacity[b];
    int cur = 0;
    float lp = 0.f;
    float* route = out + (size_t)b * RLEN;
    if (lane == 0) route[0] = 0.f;
    for (int s = 0; s < nsteps; ++s) {
        bool f1 = (!vis1) && (d1 <= cap);
        bool f2 = v2 && (!vis2) && (d2 <= cap);
        unsigned long long any = __ballot(f1 || f2);
        if (any == 0ULL) {
            if (lane == 0) route[1 + s] = 0.f;
            continue;
        }
        const float* sr = &Sl[cur * NNODE];
        const float* g = gumbel + ((size_t)s * BATCH + b) * NNODE;
        float sc1 = sr[j1];
        float sc2 = v2 ? sr[j2] : 0.f;
        float m1 = f1 ? sc1 : -1e9f;
        float m2 = f2 ? sc2 : -1e9f;
        // argmax(masked + g), first-index tie-break
        float k1 = m1 + g[j1];
        float k2 = v2 ? (m2 + g[j2]) : -INFINITY;
        float bk; int bi;
        if (k1 >= k2) { bk = k1; bi = j1; } else { bk = k2; bi = j2; }
#pragma unroll
        for (int off = 32; off; off >>= 1) {
            float ok = __shfl_xor(bk, off);
            int   oi = __shfl_xor(bi, off);
            if (ok > bk || (ok == bk && oi < bi)) { bk = ok; bi = oi; }
        }
        const int choice = bi;   // uniform across wave
        // log_softmax(masked)[choice]
        float mx = wave_max(fmaxf(m1, v2 ? m2 : -1e9f));
        float e = expf(m1 - mx) + (v2 ? expf(m2 - mx) : 0.f);
        e = wave_sum(e);
        float msel = __shfl((choice < 64) ? m1 : m2, choice & 63);
        float dsel = __shfl((choice < 64) ? d1 : d2, choice & 63);
        lp += msel - mx - logf(e);
        if (j1 == choice) vis1 = true;
        if (j2 == choice) vis2 = true;
        cap -= dsel;
        cur = choice;
        if (lane == 0) route[1 + s] = (float)choice;
    }
    if (lane == 0) out[(size_t)BATCH * RLEN + b] = lp;
}

extern "C" void kernel_launch(void* const* d_in, const int* in_sizes, int n_in,
                              void* d_out, int out_size, void* d_ws, size_t ws_size,
                              hipStream_t stream) {
    const float* node_feats = (const float*)d_in[0];
    const float* demand     = (const float*)d_in[1];
    const float* capacity   = (const float*)d_in[2];
    const float* gumbel     = (const float*)d_in[3];
    const float* W_node     = (const float*)d_in[4];
    const float* b_node     = (const float*)d_in[5];
    const float* qkv_w      = (const float*)d_in[6];
    const float* qkv_b      = (const float*)d_in[7];
    const float* out_w      = (const float*)d_in[8];
    const float* out_b      = (const float*)d_in[9];
    const float* ln1_s      = (const float*)d_in[10];
    const float* ln1_b      = (const float*)d_in[11];
    const float* w1         = (const float*)d_in[12];
    const float* b1         = (const float*)d_in[13];
    const float* w2         = (const float*)d_in[14];
    const float* b2         = (const float*)d_in[15];
    const float* ln2_s      = (const float*)d_in[16];
    const float* ln2_b      = (const float*)d_in[17];
    const int gsteps = in_sizes[3] / (BATCH * NNODE);   // 199

    float* x    = (float*)d_ws;                       // [MTOK][256]
    float* buf1 = x + (size_t)MTOK * HDIM;            // [MTOK][768] (qkv / ffn-hidden / S)
    float* S    = buf1;                               // reuse after encoder
    float* out  = (float*)d_out;

    k_embed<<<MTOK * HDIM / 256, 256, 0, stream>>>(node_feats, W_node, b_node, x);

    for (int l = 0; l < NLAYER; ++l) {
        // qkv = x @ qkv_w + qkv_b            [MTOK,768]  (NEW v2 tile — A/B test)
        k_gemm2<256, 768, false, false><<<dim3(6, MTOK / 256), 256, 0, stream>>>(
            x, 256, qkv_w + (size_t)l * 256 * 768, qkv_b + (size_t)l * 768, nullptr, buf1);
        // attention (o written into q-slice of buf1, row stride 768)
        k_attn<<<BATCH * NHEAD, 64, 0, stream>>>(buf1, buf1);
        // x = x + o @ out_w + out_b          (round-1 v1 tile)
        k_gemm<256, 256, false, true><<<dim3(2, MTOK / 128), 256, 0, stream>>>(
            buf1, 768, out_w + (size_t)l * 256 * 256, out_b + (size_t)l * 256, x, x);
        k_ln<<<MTOK / 4, 256, 0, stream>>>(x, ln1_s + (size_t)l * 256, ln1_b + (size_t)l * 256);
        // h = relu(x @ w1 + b1)              [MTOK,512]  (NEW v2 tile — A/B test)
        k_gemm2<256, 512, true, false><<<dim3(4, MTOK / 256), 256, 0, stream>>>(
            x, 256, w1 + (size_t)l * 256 * 512, b1 + (size_t)l * 512, nullptr, buf1);
        // x = x + h @ w2 + b2                (round-1 v1 tile)
        k_gemm<512, 256, false, true><<<dim3(2, MTOK / 128), 256, 0, stream>>>(
            buf1, 512, w2 + (size_t)l * 512 * 256, b2 + (size_t)l * 256, x, x);
        k_ln<<<MTOK / 4, 256, 0, stream>>>(x, ln2_s + (size_t)l * 256, ln2_b + (size_t)l * 256);
    }

    k_gram<<<BATCH, 256, 0, stream>>>(x, S);
    k_route<<<BATCH, 64, 0, stream>>>(S, demand, capacity, gumbel, out, gsteps);
    (void)n_in; (void)out_size; (void)ws_size;
}

// Round 6
// 2811.774 us; speedup vs baseline: 4.4819x; 1.1079x over previous
//
#include <hip/hip_runtime.h>
#include <math.h>
#include <stdint.h>

constexpr int BATCH  = 512;
constexpr int NNODE  = 100;
constexpr int HDIM   = 256;
constexpr int NHEAD  = 8;
constexpr int DHEAD  = 32;
constexpr int NLAYER = 3;
constexpr int FDIM   = 512;
constexpr int MTOK   = BATCH * NNODE;   // 51200
constexpr int RLEN   = 200;             // route row length = 1 + 199

static __device__ __forceinline__ float wave_sum(float v) {
#pragma unroll
    for (int o = 32; o; o >>= 1) v += __shfl_xor(v, o);
    return v;
}
static __device__ __forceinline__ float wave_max(float v) {
#pragma unroll
    for (int o = 32; o; o >>= 1) v = fmaxf(v, __shfl_xor(v, o));
    return v;
}

// ---------------- node embedding: x = node_feats @ W_node + b_node ----------------
__global__ void k_embed(const float* __restrict__ nf, const float* __restrict__ W,
                        const float* __restrict__ bias, float* __restrict__ x) {
    int idx = blockIdx.x * 256 + threadIdx.x;   // over MTOK*HDIM
    int row = idx >> 8;
    int col = idx & 255;
    float a0 = nf[row * 3 + 0], a1 = nf[row * 3 + 1], a2 = nf[row * 3 + 2];
    x[idx] = fmaf(a0, W[col], fmaf(a1, W[256 + col], fmaf(a2, W[512 + col], bias[col])));
}

// ---------------- tile GEMM v1 (round-1 exact): 128x128 tile, 8x8/thread ----------------
template<int KSIZE, int NSIZE, bool RELU, bool RES>
__global__ __launch_bounds__(256) void k_gemm(const float* __restrict__ A, int lda,
                                              const float* __restrict__ W,
                                              const float* __restrict__ bias,
                                              const float* __restrict__ res,
                                              float* __restrict__ C) {
    __shared__ alignas(16) float As[16][128];
    __shared__ alignas(16) float Bs[16][132];   // padded: conflict-free writes
    const int t  = threadIdx.x;
    const int tx = t & 15, ty = t >> 4;
    const int m0 = blockIdx.y * 128, n0 = blockIdx.x * 128;
    const int la_row = t >> 1, la_ko = (t & 1) * 8;
    const int lb_row = t >> 4, lb_col = (t & 15) * 8;
    float acc[2][4][2][4] = {};

    for (int kc = 0; kc < KSIZE; kc += 16) {
        const float* ap = &A[(size_t)(m0 + la_row) * lda + kc + la_ko];
        float4 a0 = *reinterpret_cast<const float4*>(ap);
        float4 a1 = *reinterpret_cast<const float4*>(ap + 4);
        const float* bp = &W[(size_t)(kc + lb_row) * NSIZE + n0 + lb_col];
        float4 b0 = *reinterpret_cast<const float4*>(bp);
        float4 b1 = *reinterpret_cast<const float4*>(bp + 4);
        __syncthreads();
        As[la_ko + 0][la_row] = a0.x; As[la_ko + 1][la_row] = a0.y;
        As[la_ko + 2][la_row] = a0.z; As[la_ko + 3][la_row] = a0.w;
        As[la_ko + 4][la_row] = a1.x; As[la_ko + 5][la_row] = a1.y;
        As[la_ko + 6][la_row] = a1.z; As[la_ko + 7][la_row] = a1.w;
        *reinterpret_cast<float4*>(&Bs[lb_row][lb_col])     = b0;
        *reinterpret_cast<float4*>(&Bs[lb_row][lb_col + 4]) = b1;
        __syncthreads();
#pragma unroll
        for (int k = 0; k < 16; ++k) {
            float ar[2][4], bc[2][4];
#pragma unroll
            for (int hh = 0; hh < 2; ++hh) {
                float4 av = *reinterpret_cast<const float4*>(&As[k][hh * 64 + ty * 4]);
                ar[hh][0] = av.x; ar[hh][1] = av.y; ar[hh][2] = av.z; ar[hh][3] = av.w;
                float4 bv = *reinterpret_cast<const float4*>(&Bs[k][hh * 64 + tx * 4]);
                bc[hh][0] = bv.x; bc[hh][1] = bv.y; bc[hh][2] = bv.z; bc[hh][3] = bv.w;
            }
#pragma unroll
            for (int rh = 0; rh < 2; ++rh)
#pragma unroll
            for (int r = 0; r < 4; ++r)
#pragma unroll
            for (int ch = 0; ch < 2; ++ch)
#pragma unroll
            for (int c = 0; c < 4; ++c)
                acc[rh][r][ch][c] = fmaf(ar[rh][r], bc[ch][c], acc[rh][r][ch][c]);
        }
    }

#pragma unroll
    for (int ch = 0; ch < 2; ++ch) {
        float4 bv = *reinterpret_cast<const float4*>(&bias[n0 + ch * 64 + tx * 4]);
        float bb[4] = {bv.x, bv.y, bv.z, bv.w};
#pragma unroll
        for (int rh = 0; rh < 2; ++rh)
#pragma unroll
        for (int r = 0; r < 4; ++r) {
            size_t off = (size_t)(m0 + rh * 64 + ty * 4 + r) * NSIZE + n0 + ch * 64 + tx * 4;
            float o0 = acc[rh][r][ch][0] + bb[0];
            float o1 = acc[rh][r][ch][1] + bb[1];
            float o2 = acc[rh][r][ch][2] + bb[2];
            float o3 = acc[rh][r][ch][3] + bb[3];
            if constexpr (RES) {
                float4 rv = *reinterpret_cast<const float4*>(&res[off]);
                o0 += rv.x; o1 += rv.y; o2 += rv.z; o3 += rv.w;
            }
            if constexpr (RELU) {
                o0 = fmaxf(o0, 0.f); o1 = fmaxf(o1, 0.f);
                o2 = fmaxf(o2, 0.f); o3 = fmaxf(o3, 0.f);
            }
            float4 ov = make_float4(o0, o1, o2, o3);
            *reinterpret_cast<float4*>(&C[off]) = ov;
        }
    }
}

// ---------------- tile GEMM v3: 128x256 tile, 8x16/thread, v1 staging ----------------
// Same coalesced staging as v1; only the register tile widens (B-frag 4x b128).
// LDS bytes/FMA: 96B / 128 FMA = 0.75 (v1: 1.0) -> LDS-pipe ceiling lifts ~1.4x.
template<int KSIZE, int NSIZE, bool RELU, bool RES>
__global__ __launch_bounds__(256) void k_gemm3(const float* __restrict__ A, int lda,
                                               const float* __restrict__ W,
                                               const float* __restrict__ bias,
                                               const float* __restrict__ res,
                                               float* __restrict__ C) {
    __shared__ alignas(16) float As[16][128];
    __shared__ alignas(16) float Bs[16][260];   // padded stride (260%32==4): balanced writes
    const int t  = threadIdx.x;
    const int tx = t & 15, ty = t >> 4;
    const int m0 = blockIdx.y * 128, n0 = blockIdx.x * 256;
    const int la_row = t >> 1, la_ko = (t & 1) * 8;
    const int lb_row = t >> 4, lb_c = (t & 15) * 4;
    float acc[2][4][4][4] = {};

    for (int kc = 0; kc < KSIZE; kc += 16) {
        const float* ap = &A[(size_t)(m0 + la_row) * lda + kc + la_ko];
        float4 a0 = *reinterpret_cast<const float4*>(ap);
        float4 a1 = *reinterpret_cast<const float4*>(ap + 4);
        const float* bp = &W[(size_t)(kc + lb_row) * NSIZE + n0 + lb_c];
        float4 b0 = *reinterpret_cast<const float4*>(bp);
        float4 b1 = *reinterpret_cast<const float4*>(bp + 64);
        float4 b2 = *reinterpret_cast<const float4*>(bp + 128);
        float4 b3 = *reinterpret_cast<const float4*>(bp + 192);
        __syncthreads();
        As[la_ko + 0][la_row] = a0.x; As[la_ko + 1][la_row] = a0.y;
        As[la_ko + 2][la_row] = a0.z; As[la_ko + 3][la_row] = a0.w;
        As[la_ko + 4][la_row] = a1.x; As[la_ko + 5][la_row] = a1.y;
        As[la_ko + 6][la_row] = a1.z; As[la_ko + 7][la_row] = a1.w;
        *reinterpret_cast<float4*>(&Bs[lb_row][lb_c])       = b0;
        *reinterpret_cast<float4*>(&Bs[lb_row][lb_c + 64])  = b1;
        *reinterpret_cast<float4*>(&Bs[lb_row][lb_c + 128]) = b2;
        *reinterpret_cast<float4*>(&Bs[lb_row][lb_c + 192]) = b3;
        __syncthreads();
#pragma unroll
        for (int k = 0; k < 16; ++k) {
            float ar[2][4], bc[4][4];
#pragma unroll
            for (int hh = 0; hh < 2; ++hh) {
                float4 av = *reinterpret_cast<const float4*>(&As[k][hh * 64 + ty * 4]);
                ar[hh][0] = av.x; ar[hh][1] = av.y; ar[hh][2] = av.z; ar[hh][3] = av.w;
            }
#pragma unroll
            for (int h = 0; h < 4; ++h) {
                float4 bv = *reinterpret_cast<const float4*>(&Bs[k][h * 64 + tx * 4]);
                bc[h][0] = bv.x; bc[h][1] = bv.y; bc[h][2] = bv.z; bc[h][3] = bv.w;
            }
#pragma unroll
            for (int rh = 0; rh < 2; ++rh)
#pragma unroll
            for (int r = 0; r < 4; ++r)
#pragma unroll
            for (int h = 0; h < 4; ++h)
#pragma unroll
            for (int c = 0; c < 4; ++c)
                acc[rh][r][h][c] = fmaf(ar[rh][r], bc[h][c], acc[rh][r][h][c]);
        }
    }

#pragma unroll
    for (int h = 0; h < 4; ++h) {
        float4 bv = *reinterpret_cast<const float4*>(&bias[n0 + h * 64 + tx * 4]);
        float bb[4] = {bv.x, bv.y, bv.z, bv.w};
#pragma unroll
        for (int rh = 0; rh < 2; ++rh)
#pragma unroll
        for (int r = 0; r < 4; ++r) {
            size_t off = (size_t)(m0 + rh * 64 + ty * 4 + r) * NSIZE + n0 + h * 64 + tx * 4;
            float o0 = acc[rh][r][h][0] + bb[0];
            float o1 = acc[rh][r][h][1] + bb[1];
            float o2 = acc[rh][r][h][2] + bb[2];
            float o3 = acc[rh][r][h][3] + bb[3];
            if constexpr (RES) {
                float4 rv = *reinterpret_cast<const float4*>(&res[off]);
                o0 += rv.x; o1 += rv.y; o2 += rv.z; o3 += rv.w;
            }
            if constexpr (RELU) {
                o0 = fmaxf(o0, 0.f); o1 = fmaxf(o1, 0.f);
                o2 = fmaxf(o2, 0.f); o3 = fmaxf(o3, 0.f);
            }
            float4 ov = make_float4(o0, o1, o2, o3);
            *reinterpret_cast<float4*>(&C[off]) = ov;
        }
    }
}

// deterministic 32-dot, identical accumulation order in both passes
static __device__ __forceinline__ float dot32(const float* __restrict__ q,
                                              const float* __restrict__ k) {
    float a = 0.f, b = 0.f;
#pragma unroll
    for (int d = 0; d < 32; d += 2) {
        a = fmaf(q[d],     k[d],     a);
        b = fmaf(q[d + 1], k[d + 1], b);
    }
    return a + b;
}

// ---------------- attention: one wave per (b,h); K/V staged in LDS ----------------
__global__ __launch_bounds__(64) void k_attn(const float* __restrict__ qkv,
                                             float* __restrict__ out) {
    __shared__ alignas(16) float ks[NNODE * 32];
    __shared__ alignas(16) float vs[NNODE * 32];
    const int b    = blockIdx.x >> 3;
    const int h    = blockIdx.x & 7;
    const int lane = threadIdx.x;
    const float* __restrict__ base = qkv + (size_t)b * NNODE * 768 + h * DHEAD;

    for (int idx = lane; idx < NNODE * 8; idx += 64) {
        int j = idx >> 3, c = idx & 7;
        float4 kv = *reinterpret_cast<const float4*>(base + (size_t)j * 768 + 256 + c * 4);
        float4 vv = *reinterpret_cast<const float4*>(base + (size_t)j * 768 + 512 + c * 4);
        *reinterpret_cast<float4*>(&ks[j * 32 + c * 4]) = kv;
        *reinterpret_cast<float4*>(&vs[j * 32 + c * 4]) = vv;
    }
    __syncthreads();

    const int  i1   = lane;
    const bool has2 = lane < (NNODE - 64);                  // 36 lanes have a 2nd row
    const int  i2   = has2 ? lane + 64 : 0;

    float q1[32], q2[32];
    {
        const float* p1 = base + (size_t)i1 * 768;
        const float* p2 = base + (size_t)i2 * 768;
#pragma unroll
        for (int c = 0; c < 8; ++c) {
            float4 a = *reinterpret_cast<const float4*>(p1 + c * 4);
            float4 e = *reinterpret_cast<const float4*>(p2 + c * 4);
            q1[4 * c + 0] = a.x; q1[4 * c + 1] = a.y; q1[4 * c + 2] = a.z; q1[4 * c + 3] = a.w;
            q2[4 * c + 0] = e.x; q2[4 * c + 1] = e.y; q2[4 * c + 2] = e.z; q2[4 * c + 3] = e.w;
        }
    }
    constexpr float scale = 0.17677669529663687f;           // 1/sqrt(32)

    // pass 1: exact row max
    float m1 = -INFINITY, m2 = -INFINITY;
    for (int j = 0; j < NNODE; ++j) {
        const float* kp = &ks[j * 32];
        float kk[32];
#pragma unroll
        for (int c = 0; c < 8; ++c) {
            float4 kv = *reinterpret_cast<const float4*>(kp + c * 4);
            kk[4 * c + 0] = kv.x; kk[4 * c + 1] = kv.y; kk[4 * c + 2] = kv.z; kk[4 * c + 3] = kv.w;
        }
        m1 = fmaxf(m1, dot32(q1, kk) * scale);
        m2 = fmaxf(m2, dot32(q2, kk) * scale);
    }

    // pass 2: exp-sum and P@V accumulation (in registers)
    float l1 = 0.f, l2 = 0.f;
    float o1[32] = {}, o2[32] = {};
    for (int j = 0; j < NNODE; ++j) {
        const float* kp = &ks[j * 32];
        const float* vp = &vs[j * 32];
        float kk[32];
#pragma unroll
        for (int c = 0; c < 8; ++c) {
            float4 kv = *reinterpret_cast<const float4*>(kp + c * 4);
            kk[4 * c + 0] = kv.x; kk[4 * c + 1] = kv.y; kk[4 * c + 2] = kv.z; kk[4 * c + 3] = kv.w;
        }
        float s1 = dot32(q1, kk) * scale;
        float s2 = dot32(q2, kk) * scale;
        float p1 = __expf(s1 - m1);
        float p2 = __expf(s2 - m2);
        l1 += p1;
        l2 += p2;
#pragma unroll
        for (int c = 0; c < 8; ++c) {
            float4 vv = *reinterpret_cast<const float4*>(vp + c * 4);
            o1[4 * c + 0] = fmaf(p1, vv.x, o1[4 * c + 0]);
            o1[4 * c + 1] = fmaf(p1, vv.y, o1[4 * c + 1]);
            o1[4 * c + 2] = fmaf(p1, vv.z, o1[4 * c + 2]);
            o1[4 * c + 3] = fmaf(p1, vv.w, o1[4 * c + 3]);
            o2[4 * c + 0] = fmaf(p2, vv.x, o2[4 * c + 0]);
            o2[4 * c + 1] = fmaf(p2, vv.y, o2[4 * c + 1]);
            o2[4 * c + 2] = fmaf(p2, vv.z, o2[4 * c + 2]);
            o2[4 * c + 3] = fmaf(p2, vv.w, o2[4 * c + 3]);
        }
    }

    const float inv1 = 1.f / l1;
    float* op1 = out + ((size_t)b * NNODE + i1) * 768 + h * DHEAD;
#pragma unroll
    for (int c = 0; c < 8; ++c) {
        float4 w = make_float4(o1[4 * c + 0] * inv1, o1[4 * c + 1] * inv1,
                               o1[4 * c + 2] * inv1, o1[4 * c + 3] * inv1);
        *reinterpret_cast<float4*>(op1 + c * 4) = w;
    }
    if (has2) {
        const float inv2 = 1.f / l2;
        float* op2 = out + ((size_t)b * NNODE + i2) * 768 + h * DHEAD;
#pragma unroll
        for (int c = 0; c < 8; ++c) {
            float4 w = make_float4(o2[4 * c + 0] * inv2, o2[4 * c + 1] * inv2,
                                   o2[4 * c + 2] * inv2, o2[4 * c + 3] * inv2);
            *reinterpret_cast<float4*>(op2 + c * 4) = w;
        }
    }
}

// ---------------- in-place LayerNorm over H=256, one wave per row ----------------
__global__ __launch_bounds__(256) void k_ln(float* __restrict__ x, const float* __restrict__ sc,
                                            const float* __restrict__ bp) {
    const int row = blockIdx.x * 4 + (threadIdx.x >> 6);
    const int lane = threadIdx.x & 63;
    float* rp = &x[(size_t)row * HDIM + lane * 4];
    float4 v = *reinterpret_cast<const float4*>(rp);
    float mean = wave_sum(v.x + v.y + v.z + v.w) * (1.f / 256.f);
    float d0 = v.x - mean, d1 = v.y - mean, d2 = v.z - mean, d3 = v.w - mean;
    float var = wave_sum(d0 * d0 + d1 * d1 + d2 * d2 + d3 * d3) * (1.f / 256.f);
    float inv = 1.f / sqrtf(var + 1e-5f);
    float4 sv = *reinterpret_cast<const float4*>(&sc[lane * 4]);
    float4 bv = *reinterpret_cast<const float4*>(&bp[lane * 4]);
    float4 ov;
    ov.x = fmaf(d0 * inv, sv.x, bv.x);
    ov.y = fmaf(d1 * inv, sv.y, bv.y);
    ov.z = fmaf(d2 * inv, sv.z, bv.z);
    ov.w = fmaf(d3 * inv, sv.w, bv.w);
    *reinterpret_cast<float4*>(rp) = ov;
}

// ---------------- Gram: S[b] = x[b] @ x[b]^T  (one block per batch) ----------------
__global__ __launch_bounds__(256) void k_gram(const float* __restrict__ x, float* __restrict__ S) {
    __shared__ alignas(16) float xs[16][128];
    const int b = blockIdx.x;
    const int t = threadIdx.x, tx = t & 15, ty = t >> 4;
    const int li = t >> 1, lko = (t & 1) * 8;
    float acc[8][8] = {};
    for (int kc = 0; kc < HDIM; kc += 16) {
        float va[8] = {0.f, 0.f, 0.f, 0.f, 0.f, 0.f, 0.f, 0.f};
        if (li < NNODE) {
            const float* p = &x[((size_t)b * NNODE + li) * HDIM + kc + lko];
            float4 u0 = *reinterpret_cast<const float4*>(p);
            float4 u1 = *reinterpret_cast<const float4*>(p + 4);
            va[0] = u0.x; va[1] = u0.y; va[2] = u0.z; va[3] = u0.w;
            va[4] = u1.x; va[5] = u1.y; va[6] = u1.z; va[7] = u1.w;
        }
        __syncthreads();
#pragma unroll
        for (int m = 0; m < 8; ++m) xs[lko + m][li] = va[m];
        __syncthreads();
#pragma unroll
        for (int k = 0; k < 16; ++k) {
            float ai[8], bj[8];
#pragma unroll
            for (int a = 0; a < 8; ++a) ai[a] = xs[k][ty + 16 * a];
#pragma unroll
            for (int c = 0; c < 8; ++c) bj[c] = xs[k][tx + 16 * c];
#pragma unroll
            for (int a = 0; a < 8; ++a)
#pragma unroll
                for (int c = 0; c < 8; ++c)
                    acc[a][c] = fmaf(ai[a], bj[c], acc[a][c]);
        }
    }
#pragma unroll
    for (int a = 0; a < 8; ++a) {
        int i = ty + 16 * a;
        if (i < NNODE) {
#pragma unroll
            for (int c = 0; c < 8; ++c) {
                int j = tx + 16 * c;
                if (j < NNODE) S[(size_t)b * NNODE * NNODE + (size_t)i * NNODE + j] = acc[a][c];
            }
        }
    }
}

// ---------------- routing decode: one wave per batch; S[b] staged in LDS ----------------
__global__ __launch_bounds__(64) void k_route(const float* __restrict__ S, const float* __restrict__ demand,
                                              const float* __restrict__ capacity,
                                              const float* __restrict__ gumbel,
                                              float* __restrict__ out, int nsteps) {
    __shared__ alignas(16) float Sl[NNODE * NNODE];   // 40 KB
    const int b = blockIdx.x;
    const int lane = threadIdx.x;
    const float* Sb = S + (size_t)b * NNODE * NNODE;
    for (int i = lane; i < NNODE * NNODE / 4; i += 64)
        *reinterpret_cast<float4*>(&Sl[i * 4]) = *reinterpret_cast<const float4*>(&Sb[i * 4]);
    __syncthreads();

    const int j1 = lane, j2 = lane + 64;
    const bool v2 = (j2 < NNODE);
    const float d1 = demand[(size_t)b * NNODE + j1];
    const float d2 = v2 ? demand[(size_t)b * NNODE + j2] : 0.f;
    bool vis1 = (j1 == 0), vis2 = false;
    float cap = capacity[b];
    int cur = 0;
    float lp = 0.f;
    float* route = out + (size_t)b * RLEN;
    if (lane == 0) route[0] = 0.f;
    for (int s = 0; s < nsteps; ++s) {
        bool f1 = (!vis1) && (d1 <= cap);
        bool f2 = v2 && (!vis2) && (d2 <= cap);
        unsigned long long any = __ballot(f1 || f2);
        if (any == 0ULL) {
            if (lane == 0) route[1 + s] = 0.f;
            continue;
        }
        const float* sr = &Sl[cur * NNODE];
        const float* g = gumbel + ((size_t)s * BATCH + b) * NNODE;
        float sc1 = sr[j1];
        float sc2 = v2 ? sr[j2] : 0.f;
        float m1 = f1 ? sc1 : -1e9f;
        float m2 = f2 ? sc2 : -1e9f;
        // argmax(masked + g), first-index tie-break
        float k1 = m1 + g[j1];
        float k2 = v2 ? (m2 + g[j2]) : -INFINITY;
        float bk; int bi;
        if (k1 >= k2) { bk = k1; bi = j1; } else { bk = k2; bi = j2; }
#pragma unroll
        for (int off = 32; off; off >>= 1) {
            float ok = __shfl_xor(bk, off);
            int   oi = __shfl_xor(bi, off);
            if (ok > bk || (ok == bk && oi < bi)) { bk = ok; bi = oi; }
        }
        const int choice = bi;   // uniform across wave
        // log_softmax(masked)[choice]
        float mx = wave_max(fmaxf(m1, v2 ? m2 : -1e9f));
        float e = expf(m1 - mx) + (v2 ? expf(m2 - mx) : 0.f);
        e = wave_sum(e);
        float msel = __shfl((choice < 64) ? m1 : m2, choice & 63);
        float dsel = __shfl((choice < 64) ? d1 : d2, choice & 63);
        lp += msel - mx - logf(e);
        if (j1 == choice) vis1 = true;
        if (j2 == choice) vis2 = true;
        cap -= dsel;
        cur = choice;
        if (lane == 0) route[1 + s] = (float)choice;
    }
    if (lane == 0) out[(size_t)BATCH * RLEN + b] = lp;
}

extern "C" void kernel_launch(void* const* d_in, const int* in_sizes, int n_in,
                              void* d_out, int out_size, void* d_ws, size_t ws_size,
                              hipStream_t stream) {
    const float* node_feats = (const float*)d_in[0];
    const float* demand     = (const float*)d_in[1];
    const float* capacity   = (const float*)d_in[2];
    const float* gumbel     = (const float*)d_in[3];
    const float* W_node     = (const float*)d_in[4];
    const float* b_node     = (const float*)d_in[5];
    const float* qkv_w      = (const float*)d_in[6];
    const float* qkv_b      = (const float*)d_in[7];
    const float* out_w      = (const float*)d_in[8];
    const float* out_b      = (const float*)d_in[9];
    const float* ln1_s      = (const float*)d_in[10];
    const float* ln1_b      = (const float*)d_in[11];
    const float* w1         = (const float*)d_in[12];
    const float* b1         = (const float*)d_in[13];
    const float* w2         = (const float*)d_in[14];
    const float* b2         = (const float*)d_in[15];
    const float* ln2_s      = (const float*)d_in[16];
    const float* ln2_b      = (const float*)d_in[17];
    const int gsteps = in_sizes[3] / (BATCH * NNODE);   // 199

    float* x    = (float*)d_ws;                       // [MTOK][256]
    float* buf1 = x + (size_t)MTOK * HDIM;            // [MTOK][768] (qkv / ffn-hidden / S)
    float* S    = buf1;                               // reuse after encoder
    float* out  = (float*)d_out;

    k_embed<<<MTOK * HDIM / 256, 256, 0, stream>>>(node_feats, W_node, b_node, x);

    for (int l = 0; l < NLAYER; ++l) {
        // qkv = x @ qkv_w + qkv_b            [MTOK,768]  (v3: 128x256 tile)
        k_gemm3<256, 768, false, false><<<dim3(3, MTOK / 128), 256, 0, stream>>>(
            x, 256, qkv_w + (size_t)l * 256 * 768, qkv_b + (size_t)l * 768, nullptr, buf1);
        // attention (o written into q-slice of buf1, row stride 768)
        k_attn<<<BATCH * NHEAD, 64, 0, stream>>>(buf1, buf1);
        // x = x + o @ out_w + out_b          (v1 control arm)
        k_gemm<256, 256, false, true><<<dim3(2, MTOK / 128), 256, 0, stream>>>(
            buf1, 768, out_w + (size_t)l * 256 * 256, out_b + (size_t)l * 256, x, x);
        k_ln<<<MTOK / 4, 256, 0, stream>>>(x, ln1_s + (size_t)l * 256, ln1_b + (size_t)l * 256);
        // h = relu(x @ w1 + b1)              [MTOK,512]  (v3)
        k_gemm3<256, 512, true, false><<<dim3(2, MTOK / 128), 256, 0, stream>>>(
            x, 256, w1 + (size_t)l * 256 * 512, b1 + (size_t)l * 512, nullptr, buf1);
        // x = x + h @ w2 + b2                (v3)
        k_gemm3<512, 256, false, true><<<dim3(1, MTOK / 128), 256, 0, stream>>>(
            buf1, 512, w2 + (size_t)l * 512 * 256, b2 + (size_t)l * 256, x, x);
        k_ln<<<MTOK / 4, 256, 0, stream>>>(x, ln2_s + (size_t)l * 256, ln2_b + (size_t)l * 256);
    }

    k_gram<<<BATCH, 256, 0, stream>>>(x, S);
    k_route<<<BATCH, 64, 0, stream>>>(S, demand, capacity, gumbel, out, gsteps);
    (void)n_in; (void)out_size; (void)ws_size;
}